// Round 9
// baseline (539.695 us; speedup 1.0000x reference)
//
#include <hip/hip_runtime.h>
#include <hip/hip_bf16.h>

// RNN: h_t = tanh(x_t U + h_{t-1} W + b), return h_T.  B=256 T=512 D=K=256.
// SINGLE fused kernel, 1040 blocks x 512 threads:
//   blocks 0..15   : transpose-U slice, then the r6 scan (verbatim structure)
//   blocks 16..1039: xU GEMM, one 128-row m-tile x both 128-col halves per
//                    block (halves share the A tile in LDS: x read once).
//                    Grid is t-quarter-major: g>>8 = quarter, so xu[t<128k]
//                    is complete early and the scan runs CONCURRENTLY.
// Sync: ws flags. flags[0]=Ut done (16 producers); flags[1+q]=quarter q done
// (256 producers each).  RELEASE atomic add after __syncthreads (drains
// stores to L2) -> cross-XCD writeback; ACQUIRE poll by tid0 + s_barrier
// (invalidates stale L1/L2).  Scan polls quarter q+1 at t==128q+124, before
// any ring prefetch crosses the boundary.  No deadlock possible: producers
// never wait; flags re-zeroed per replay by in-graph hipMemsetAsync; Ut/xu
// fully rewritten before any flag-gated read (re-poison-proof).

typedef _Float16 half8_t __attribute__((ext_vector_type(8)));
typedef _Float16 half2_t __attribute__((ext_vector_type(2)));
typedef float    float4_t __attribute__((ext_vector_type(4)));

#define MFMA16(a, b, c) __builtin_amdgcn_mfma_f32_16x16x32_f16((a), (b), (c), 0, 0, 0)

__device__ __forceinline__ half2_t pk_h2(float a, float b) {
    auto r = __builtin_amdgcn_cvt_pkrtz(a, b);
    return __builtin_bit_cast(half2_t, r);
}

__device__ __forceinline__ float fast_tanh(float x) {
    float e = __builtin_amdgcn_exp2f(2.8853900817779268f * x);
    return 1.0f - 2.0f * __builtin_amdgcn_rcpf(e + 1.0f);
}

// LDS-only barrier: order h dbuf write->read WITHOUT draining vmem prefetches.
__device__ __forceinline__ void lds_barrier() {
    __builtin_amdgcn_sched_barrier(0);
    asm volatile("s_waitcnt lgkmcnt(0)" ::: "memory");
    __builtin_amdgcn_s_barrier();
    __builtin_amdgcn_sched_barrier(0);
}

// Block-wide wait: tid0 ACQUIRE-polls the flag (invalidates L1/L2 on success
// path), all other waves park at s_barrier.  Uniform call site per block.
__device__ __forceinline__ void wait_flag(unsigned* f, unsigned target) {
    if (threadIdx.x == 0) {
        while (__hip_atomic_load(f, __ATOMIC_ACQUIRE, __HIP_MEMORY_SCOPE_AGENT) < target)
            __builtin_amdgcn_s_sleep(16);
    }
    __builtin_amdgcn_sched_barrier(0);
    __builtin_amdgcn_s_barrier();
    __builtin_amdgcn_sched_barrier(0);
    asm volatile("" ::: "memory");
}

__global__ __launch_bounds__(512, 2) void fused(
    const float* __restrict__ x,        // [B*T][256] fp32 (m = b*512+t)
    const float* __restrict__ U,        // [256][256] fp32
    const float* __restrict__ W,        // [256][256] fp32
    const float* __restrict__ bias,     // [256]
    _Float16* __restrict__ Ut,          // ws: [256][264] fp16
    half2_t* __restrict__ xu,           // ws: [B*T][128] half2 (bias folded)
    unsigned* __restrict__ flags,       // ws: [0]=ut_done, [1..4]=quarter done
    float* __restrict__ out)            // [256][256] fp32
{
    __shared__ char lds[61440];
    const int tid = threadIdx.x;

    if (blockIdx.x < 16) {
        // ================= SCAN ROLE (+ transpose prologue) =================
        const int lane = tid & 63, w8 = tid >> 6, l15 = lane & 15, q4 = lane >> 4;
        const int blk = blockIdx.x;
        const int c0 = 32 * w8 + 2 * l15;

        // ---- transpose slice: 16 blk x 512 thr x 8 elems = 65536 ----
        {
            int idx = blk * 512 + tid;                  // 0..8191
            const float4* up = (const float4*)U + (size_t)idx * 2;
            float4 u0 = up[0], u1 = up[1];
            int d = idx >> 5, n = (idx & 31) * 8;
            _Float16* dst = Ut + (size_t)n * 264 + d;
            dst[0 * 264] = (_Float16)u0.x;  dst[1 * 264] = (_Float16)u0.y;
            dst[2 * 264] = (_Float16)u0.z;  dst[3 * 264] = (_Float16)u0.w;
            dst[4 * 264] = (_Float16)u1.x;  dst[5 * 264] = (_Float16)u1.y;
            dst[6 * 264] = (_Float16)u1.z;  dst[7 * 264] = (_Float16)u1.w;
        }
        __syncthreads();   // drains all waves' Ut stores to L2
        if (tid == 0)
            __hip_atomic_fetch_add(&flags[0], 1u, __ATOMIC_RELEASE,
                                   __HIP_MEMORY_SCOPE_AGENT);

        // ---- W -> B-frags in registers (overlaps gemm's quarter 0) ----
        half8_t wf[2][8];
#pragma unroll
        for (int tt = 0; tt < 2; ++tt)
#pragma unroll
            for (int c = 0; c < 8; ++c) {
                half8_t f;
#pragma unroll
                for (int j = 0; j < 8; ++j) {
                    int k = 32 * c + q4 * 8 + j;
                    f[j] = (_Float16)W[k * 256 + c0 + tt];
                }
                wf[tt][c] = f;
            }

        // h0 = 0 (both buffers)
        for (int i = tid; i < 16896 / 4; i += 512) ((int*)lds)[i] = 0;

        const int rowg0 = 16 * blk + q4 * 4;
        const int colh = c0 >> 1;

        unsigned xoff[4];
#pragma unroll
        for (int i = 0; i < 4; ++i)
            xoff[i] = (unsigned)(rowg0 + i) * 512u * 128u + (unsigned)colh;

        // wait for xu quarter 0 (t in [0,128)) before touching xu
        wait_flag(&flags[1], 256);

        half2_t xr[4][4];
#pragma unroll
        for (int p = 0; p < 4; ++p)
#pragma unroll
            for (int i = 0; i < 4; ++i)
                xr[p][i] = xu[xoff[i] + (unsigned)p * 128u];
#pragma unroll
        for (int i = 0; i < 4; ++i) xoff[i] += 512u;

        char* const L = (char*)lds;
        const int afb = l15 * 528 + q4 * 16;       // ds_read base + imm
        const int hwb = (q4 * 4) * 528 + c0 * 2;   // ds_write base + imm

        __syncthreads();

#define SCAN_STEP(P_, PAR, DOPF, LAST)                                          \
    {                                                                           \
        const char* hcur = L + ((PAR) ? 8448 : 0);                              \
        half8_t af[8];                                                          \
        _Pragma("unroll")                                                       \
        for (int c8 = 0; c8 < 8; ++c8)                                          \
            af[c8] = *(const half8_t*)(hcur + afb + c8 * 64);                   \
        float4_t a0a, a1a, a0b, a1b;                                            \
        _Pragma("unroll")                                                       \
        for (int i = 0; i < 4; ++i) {                                           \
            a0a[i] = (float)xr[P_][i][0];                                       \
            a1a[i] = (float)xr[P_][i][1];                                       \
            a0b[i] = 0.f; a1b[i] = 0.f;                                         \
        }                                                                       \
        if (DOPF) {                                                             \
            _Pragma("unroll")                                                   \
            for (int i = 0; i < 4; ++i) {                                       \
                xr[P_][i] = xu[xoff[i]];                                        \
                xoff[i] += 128u;                                                \
            }                                                                   \
        }                                                                       \
        _Pragma("unroll")                                                       \
        for (int c = 0; c < 4; ++c) {                                           \
            a0a = MFMA16(af[2 * c],     wf[0][2 * c],     a0a);                 \
            a1a = MFMA16(af[2 * c],     wf[1][2 * c],     a1a);                 \
            a0b = MFMA16(af[2 * c + 1], wf[0][2 * c + 1], a0b);                 \
            a1b = MFMA16(af[2 * c + 1], wf[1][2 * c + 1], a1b);                 \
        }                                                                       \
        if (LAST) {                                                             \
            _Pragma("unroll")                                                   \
            for (int i = 0; i < 4; ++i) {                                       \
                float2 st;                                                      \
                st.x = fast_tanh(a0a[i] + a0b[i]);                              \
                st.y = fast_tanh(a1a[i] + a1b[i]);                              \
                *(float2*)(&out[(rowg0 + i) * 256 + c0]) = st;                  \
            }                                                                   \
        } else {                                                                \
            char* hnext = L + ((PAR) ? 0 : 8448);                               \
            _Pragma("unroll")                                                   \
            for (int i = 0; i < 4; ++i) {                                       \
                float v0 = fast_tanh(a0a[i] + a0b[i]);                          \
                float v1 = fast_tanh(a1a[i] + a1b[i]);                          \
                *(half2_t*)(hnext + hwb + i * 528) = pk_h2(v0, v1);             \
            }                                                                   \
            lds_barrier();                                                      \
        }                                                                       \
    }

        // main: t = 0..507; poll quarter q+1 at t = 128q+124, i.e. before the
        // steps whose prefetch (t+4) first crosses into quarter q+1.
        for (int t4 = 0; t4 < 508; t4 += 4) {
            if ((t4 & 127) == 124) wait_flag(&flags[2 + (t4 >> 7)], 256);
            SCAN_STEP(0, 0, 1, 0)
            SCAN_STEP(1, 1, 1, 0)
            SCAN_STEP(2, 0, 1, 0)
            SCAN_STEP(3, 1, 1, 0)
        }
        // peeled tail t = 508..511: ring already holds xu[508..511]
        SCAN_STEP(0, 0, 0, 0)
        SCAN_STEP(1, 1, 0, 0)
        SCAN_STEP(2, 0, 0, 0)
        SCAN_STEP(3, 1, 0, 1)
#undef SCAN_STEP

    } else {
        // ================= GEMM ROLE =================
        // g in [0,1024): qt = g>>8 (t-quarter, dispatched in order), b = g&255.
        // m-tile rows [b*512 + qt*128, +128).  Halves h=0/1 do cols [128h,+128).
        const int g  = blockIdx.x - 16;
        const int qt = g >> 8;
        const int bb = g & 255;
        const size_t m0 = ((size_t)bb * 4 + qt) * 128;
        const int h  = tid >> 8;            // col half
        const int tl = tid & 255;
        const int n0 = h * 128;
        const int lane = tl & 63, w = tl >> 6, l15 = lane & 15, q4 = lane >> 4;

        // wait until Ut is fully written (acquire invalidates stale cache)
        wait_flag(&flags[0], 16);

        char* const As0 = lds;                      // shared by both halves
        char* const Bs0 = lds + 20480 + h * 20480;  // per-half

        float4 ar[4];
        uint4  br[2];

        auto loadA = [&](int it) {
            if (h == 0) {
#pragma unroll
                for (int i = 0; i < 4; ++i) {
                    int u = tl + 256 * i, row = u >> 3, sg = u & 7;
                    ar[i] = *(const float4*)(x + (m0 + row) * 256 + it * 32 + sg * 4);
                }
            }
        };
        auto loadB = [&](int it) {
#pragma unroll
            for (int i = 0; i < 2; ++i) {
                int u = tl + 256 * i, p = u >> 2, sg = u & 3;
                int c = n0 + 32 * (p >> 5) + 2 * (p & 15) + ((p >> 4) & 1);
                br[i] = *(const uint4*)((const char*)Ut + c * 528 + it * 64 + sg * 16);
            }
        };
        auto writeAB = [&](int s) {
            if (h == 0) {
                char* As = As0 + s * 10240;
#pragma unroll
                for (int i = 0; i < 4; ++i) {
                    int u = tl + 256 * i, row = u >> 3, sg = u & 7;
                    uint2 v;
                    v.x = __builtin_bit_cast(unsigned, pk_h2(ar[i].x, ar[i].y));
                    v.y = __builtin_bit_cast(unsigned, pk_h2(ar[i].z, ar[i].w));
                    *(uint2*)(As + row * 80 + sg * 8) = v;
                }
            }
            char* Bs = Bs0 + s * 10240;
#pragma unroll
            for (int i = 0; i < 2; ++i) {
                int u = tl + 256 * i, p = u >> 2, sg = u & 3;
                *(uint4*)(Bs + p * 80 + sg * 16) = br[i];
            }
        };

        float4_t acc[16];
#pragma unroll
        for (int i = 0; i < 16; ++i) {
            acc[i][0] = 0.f; acc[i][1] = 0.f; acc[i][2] = 0.f; acc[i][3] = 0.f;
        }

        loadA(0); loadB(0); writeAB(0);
        __syncthreads();

        for (int it = 0; it < 8; ++it) {
            if (it < 7) { loadA(it + 1); loadB(it + 1); }
            const char* As = As0 + (it & 1) * 10240;
            const char* Bs = Bs0 + (it & 1) * 10240;
            half8_t af[2];
#pragma unroll
            for (int ms = 0; ms < 2; ++ms)
                af[ms] = *(const half8_t*)(As + (32 * w + 16 * ms + l15) * 80 + q4 * 16);
#pragma unroll
            for (int ns = 0; ns < 8; ++ns) {
                half8_t bf = *(const half8_t*)(Bs + (16 * ns + l15) * 80 + q4 * 16);
                acc[ns * 2 + 0] = MFMA16(af[0], bf, acc[ns * 2 + 0]);
                acc[ns * 2 + 1] = MFMA16(af[1], bf, acc[ns * 2 + 1]);
            }
            if (it < 7) writeAB((it + 1) & 1);
            __syncthreads();
        }

        // epilogue: + bias, pack col pairs, store
#pragma unroll
        for (int ms = 0; ms < 2; ++ms)
#pragma unroll
            for (int j = 0; j < 4; ++j) {
                const int c = n0 + 32 * j + 2 * l15;
                const float2 bv = *(const float2*)(bias + c);
#pragma unroll
                for (int i = 0; i < 4; ++i) {
                    float v0 = acc[(2 * j) * 2 + ms][i] + bv.x;
                    float v1 = acc[(2 * j + 1) * 2 + ms][i] + bv.y;
                    int m_g = (int)m0 + 32 * w + 16 * ms + q4 * 4 + i;
                    xu[(size_t)m_g * 128 + (c >> 1)] = pk_h2(v0, v1);
                }
            }

        __syncthreads();   // drains all waves' xu stores to L2
        if (tid == 0)
            __hip_atomic_fetch_add(&flags[1 + qt], 1u, __ATOMIC_RELEASE,
                                   __HIP_MEMORY_SCOPE_AGENT);
    }
}

extern "C" void kernel_launch(void* const* d_in, const int* in_sizes, int n_in,
                              void* d_out, int out_size, void* d_ws, size_t ws_size,
                              hipStream_t stream) {
    const float* x = (const float*)d_in[0];   // [256,512,256]
    const float* U = (const float*)d_in[1];   // [256,256]
    const float* W = (const float*)d_in[2];   // [256,256]
    const float* b = (const float*)d_in[3];   // [256]
    float* out = (float*)d_out;

    char* ws = (char*)d_ws;
    _Float16* Ut   = (_Float16*)ws;                 // 256*264*2 = 135168 B
    unsigned* flags = (unsigned*)(ws + 196608);     // 5 u32, in Ut..xu gap
    half2_t*  xu   = (half2_t*)(ws + 262144);       // 64 MB
    // requires ws_size >= 67,371,008 B (unchanged)

    hipMemsetAsync(flags, 0, 64, stream);           // re-zero flags per replay
    fused<<<1040, 512, 0, stream>>>(x, U, W, b, Ut, xu, flags, out);
}